// Round 1
// baseline (1624.560 us; speedup 1.0000x reference)
//
#include <hip/hip_runtime.h>
#include <math.h>

#define TT 2048
#define HH 2048
#define ID 768
#define NE 32
#define KTOP 8
#define CAP 1024

typedef short bf16x8 __attribute__((ext_vector_type(8)));
typedef float f32x4 __attribute__((ext_vector_type(4)));

__device__ __forceinline__ unsigned short f2b(float f) {
  unsigned int u = __builtin_bit_cast(unsigned int, f);
  u += 0x7fff + ((u >> 16) & 1);   // round-to-nearest-even
  return (unsigned short)(u >> 16);
}

// ---------------- x -> bf16 pre-convert ----------------
__global__ __launch_bounds__(256) void cvt_x_kernel(const float* __restrict__ x,
                                                    unsigned short* __restrict__ xb) {
  const size_t i = ((size_t)blockIdx.x * 256 + threadIdx.x) * 8;
  const float4 a = *(const float4*)(x + i);
  const float4 b = *(const float4*)(x + i + 4);
  union { unsigned short us[8]; uint4 v; } p;
  p.us[0] = f2b(a.x); p.us[1] = f2b(a.y); p.us[2] = f2b(a.z); p.us[3] = f2b(a.w);
  p.us[4] = f2b(b.x); p.us[5] = f2b(b.y); p.us[6] = f2b(b.z); p.us[7] = f2b(b.w);
  *(uint4*)(xb + i) = p.v;
}

// ---------------- router: logits (f64 acc) + top-8 + assign ----------------
__global__ __launch_bounds__(64) void router_kernel(
    const float* __restrict__ x, const float* __restrict__ gw,
    const float* __restrict__ gb, int* __restrict__ counts,
    int* __restrict__ tok_slot, float* __restrict__ w_slot) {
  const int t = blockIdx.x;
  const int lane = threadIdx.x;
  const int e = lane & 31;
  const int half = lane >> 5;
  const float* xr = x + (size_t)t * HH;
  double acc = 0.0;
  const int j0 = half * (HH / 2), j1 = j0 + HH / 2;
  for (int j = j0; j < j1; ++j)
    acc = fma((double)xr[j], (double)gw[j * NE + e], acc);
  acc += __shfl_xor(acc, 32);
  __shared__ float logits[NE];
  if (half == 0) logits[e] = (float)acc + gb[e];
  __syncthreads();
  if (lane == 0) {
    float l[NE];
    float m = -1e30f;
    for (int i = 0; i < NE; ++i) { l[i] = logits[i]; m = fmaxf(m, l[i]); }
    int sel[KTOP]; float ex[KTOP]; float s = 0.f;
    for (int k = 0; k < KTOP; ++k) {
      float best = -1e30f; int bi = 0;
      for (int i = 0; i < NE; ++i)
        if (l[i] > best) { best = l[i]; bi = i; }   // strict > : lowest index on ties (jax)
      sel[k] = bi;
      ex[k] = expf(best - m);
      s += ex[k];
      l[bi] = -1e31f;
    }
    const float inv = 1.f / s;
    for (int k = 0; k < KTOP; ++k) {
      const int ee = sel[k];
      const int pos = atomicAdd(&counts[ee], 1);
      if (pos < CAP) {
        tok_slot[ee * CAP + pos] = t;
        w_slot[ee * CAP + pos] = ex[k] * inv;
      }
    }
  }
}

// ---------------- expert gate_up GEMM + SiLU*mul ----------------
// grid: (I/64, CAP/128, E); block 256. Tile: 128(M) x 64(N for g AND u), BK=32.
__global__ __launch_bounds__(256) void gu_kernel(
    const unsigned short* __restrict__ xb, const float* __restrict__ wgu,
    const int* __restrict__ counts, const int* __restrict__ tok_slot,
    unsigned short* __restrict__ h_ws) {
  const int e = blockIdx.z, mt = blockIdx.y, nt = blockIdx.x;
  int cnt = counts[e]; cnt = cnt > CAP ? CAP : cnt;
  if (mt * 128 >= cnt) return;

  __shared__ __align__(16) unsigned short As[128][40];
  __shared__ __align__(16) unsigned short Bg[64][40];
  __shared__ __align__(16) unsigned short Bu[64][40];
  __shared__ int toks[128];

  const int tid = threadIdx.x;
  if (tid < 128) toks[tid] = tok_slot[e * CAP + mt * 128 + tid];
  __syncthreads();

  const float* wg = wgu + (size_t)e * HH * (2 * ID) + nt * 64;
  const float* wu = wg + ID;

  const int wid = tid >> 6, lane = tid & 63;
  const int wm = wid & 1, wn = wid >> 1;
  const int lr = lane & 15, quad = lane >> 4;

  f32x4 accg[4][2], accu[4][2];
  for (int s = 0; s < 4; ++s)
    for (int t = 0; t < 2; ++t)
      for (int r = 0; r < 4; ++r) { accg[s][t][r] = 0.f; accu[s][t][r] = 0.f; }

  for (int k0 = 0; k0 < HH; k0 += 32) {
    // stage A (gathered x rows, already bf16): 128 rows x 32 k
#pragma unroll
    for (int it = 0; it < 2; ++it) {
      const int task = tid + it * 256;
      const int row = task >> 2, cg = task & 3;
      const uint4 v = *(const uint4*)(xb + (size_t)toks[row] * HH + k0 + cg * 8);
      *(uint4*)&As[row][cg * 8] = v;
    }
    // stage B (g and u slices), f32 -> bf16, transposed to [n][k]
#pragma unroll
    for (int it = 0; it < 2; ++it) {
      const int task = tid + it * 256;
      const int k = task >> 4, cg = task & 15;
      const size_t off = (size_t)(k0 + k) * (2 * ID) + cg * 4;
      const float4 vg = *(const float4*)(wg + off);
      const float4 vu = *(const float4*)(wu + off);
      Bg[cg * 4 + 0][k] = f2b(vg.x); Bg[cg * 4 + 1][k] = f2b(vg.y);
      Bg[cg * 4 + 2][k] = f2b(vg.z); Bg[cg * 4 + 3][k] = f2b(vg.w);
      Bu[cg * 4 + 0][k] = f2b(vu.x); Bu[cg * 4 + 1][k] = f2b(vu.y);
      Bu[cg * 4 + 2][k] = f2b(vu.z); Bu[cg * 4 + 3][k] = f2b(vu.w);
    }
    __syncthreads();
    bf16x8 af[4];
#pragma unroll
    for (int s = 0; s < 4; ++s)
      af[s] = *(const bf16x8*)&As[wm * 64 + s * 16 + lr][quad * 8];
#pragma unroll
    for (int t = 0; t < 2; ++t) {
      const bf16x8 bg = *(const bf16x8*)&Bg[wn * 32 + t * 16 + lr][quad * 8];
      const bf16x8 bu = *(const bf16x8*)&Bu[wn * 32 + t * 16 + lr][quad * 8];
#pragma unroll
      for (int s = 0; s < 4; ++s) {
        accg[s][t] = __builtin_amdgcn_mfma_f32_16x16x32_bf16(af[s], bg, accg[s][t], 0, 0, 0);
        accu[s][t] = __builtin_amdgcn_mfma_f32_16x16x32_bf16(af[s], bu, accu[s][t], 0, 0, 0);
      }
    }
    __syncthreads();
  }

  unsigned short* hb = h_ws + (size_t)(e * CAP + mt * 128) * ID + nt * 64;
#pragma unroll
  for (int s = 0; s < 4; ++s)
#pragma unroll
    for (int t = 0; t < 2; ++t)
#pragma unroll
      for (int r = 0; r < 4; ++r) {
        const int row = wm * 64 + s * 16 + quad * 4 + r;
        const int col = wn * 32 + t * 16 + lr;
        const float g = accg[s][t][r], u = accu[s][t][r];
        const float h = (g / (1.f + __expf(-g))) * u;
        hb[(size_t)row * ID + col] = f2b(h);
      }
}

// ---------------- expert down GEMM + weight-scale + scatter-add ----------------
// grid: (H/128, CAP/128, E); block 256. Tile: 128x128, K=768, BK=32.
__global__ __launch_bounds__(256) void down_kernel(
    const unsigned short* __restrict__ h_ws, const float* __restrict__ wd,
    const int* __restrict__ counts, const int* __restrict__ tok_slot,
    const float* __restrict__ w_slot, float* __restrict__ out) {
  const int e = blockIdx.z, mt = blockIdx.y;
  const int nb = blockIdx.x * 128;
  int cnt = counts[e]; cnt = cnt > CAP ? CAP : cnt;
  if (mt * 128 >= cnt) return;

  __shared__ __align__(16) unsigned short As[128][40];
  __shared__ __align__(16) unsigned short Bs[128][40];
  __shared__ int toks[128];
  __shared__ float wr[128];

  const int tid = threadIdx.x;
  if (tid < 128) {
    toks[tid] = tok_slot[e * CAP + mt * 128 + tid];
    wr[tid] = w_slot[e * CAP + mt * 128 + tid];
  }

  const unsigned short* hb = h_ws + (size_t)(e * CAP + mt * 128) * ID;
  const float* wb = wd + (size_t)e * ID * HH + nb;

  const int wid = tid >> 6, lane = tid & 63;
  const int wm = wid & 1, wn = wid >> 1;
  const int lr = lane & 15, quad = lane >> 4;

  f32x4 acc[4][4];
  for (int s = 0; s < 4; ++s)
    for (int t = 0; t < 4; ++t)
      for (int r = 0; r < 4; ++r) acc[s][t][r] = 0.f;

  for (int k0 = 0; k0 < ID; k0 += 32) {
#pragma unroll
    for (int it = 0; it < 2; ++it) {
      const int task = tid + it * 256;
      const int row = task >> 2, cg = task & 3;
      const uint4 v = *(const uint4*)(hb + (size_t)row * ID + k0 + cg * 8);
      *(uint4*)&As[row][cg * 8] = v;
    }
#pragma unroll
    for (int it = 0; it < 4; ++it) {
      const int task = tid + it * 256;
      const int k = task >> 5, cg = task & 31;
      const float4 v = *(const float4*)(wb + (size_t)(k0 + k) * HH + cg * 4);
      Bs[cg * 4 + 0][k] = f2b(v.x); Bs[cg * 4 + 1][k] = f2b(v.y);
      Bs[cg * 4 + 2][k] = f2b(v.z); Bs[cg * 4 + 3][k] = f2b(v.w);
    }
    __syncthreads();
    bf16x8 af[4], bfr[4];
#pragma unroll
    for (int s = 0; s < 4; ++s)
      af[s] = *(const bf16x8*)&As[wm * 64 + s * 16 + lr][quad * 8];
#pragma unroll
    for (int t = 0; t < 4; ++t)
      bfr[t] = *(const bf16x8*)&Bs[wn * 64 + t * 16 + lr][quad * 8];
#pragma unroll
    for (int s = 0; s < 4; ++s)
#pragma unroll
      for (int t = 0; t < 4; ++t)
        acc[s][t] = __builtin_amdgcn_mfma_f32_16x16x32_bf16(af[s], bfr[t], acc[s][t], 0, 0, 0);
    __syncthreads();
  }

#pragma unroll
  for (int s = 0; s < 4; ++s) {
#pragma unroll
    for (int r = 0; r < 4; ++r) {
      const int row = wm * 64 + s * 16 + quad * 4 + r;
      const float w = wr[row];
      if (w != 0.f) {
        const int tk = toks[row];
        float* op = out + (size_t)tk * HH + nb + wn * 64 + lr;
#pragma unroll
        for (int t = 0; t < 4; ++t)
          atomicAdd(op + t * 16, acc[s][t][r] * w);
      }
    }
  }
}

extern "C" void kernel_launch(void* const* d_in, const int* in_sizes, int n_in,
                              void* d_out, int out_size, void* d_ws, size_t ws_size,
                              hipStream_t stream) {
  const float* x   = (const float*)d_in[0];
  const float* gw  = (const float*)d_in[1];
  const float* gb  = (const float*)d_in[2];
  const float* wgu = (const float*)d_in[3];
  const float* wd  = (const float*)d_in[4];
  float* out = (float*)d_out;

  char* ws = (char*)d_ws;
  int*   counts   = (int*)ws;                               // 128 B (pad to 256)
  int*   tok_slot = (int*)(ws + 256);                       // 131072 B
  float* w_slot   = (float*)(ws + 256 + 131072);            // 131072 B
  unsigned short* xb   = (unsigned short*)(ws + 262656);    // 8 MB bf16 x
  unsigned short* h_ws = (unsigned short*)(ws + 262656 + 8388608);  // 50 MB bf16 h

  hipMemsetAsync(d_ws, 0, 262400, stream);                  // counts + slots (w=0 pads)
  hipMemsetAsync(d_out, 0, (size_t)out_size * sizeof(float), stream);

  cvt_x_kernel<<<dim3((TT * HH) / (256 * 8)), dim3(256), 0, stream>>>(x, xb);
  router_kernel<<<dim3(TT), dim3(64), 0, stream>>>(x, gw, gb, counts, tok_slot, w_slot);
  gu_kernel<<<dim3(ID / 64, CAP / 128, NE), dim3(256), 0, stream>>>(xb, wgu, counts, tok_slot, h_ws);
  down_kernel<<<dim3(HH / 128, CAP / 128, NE), dim3(256), 0, stream>>>(h_ws, wd, counts, tok_slot, w_slot, out);
}

// Round 2
// 1287.553 us; speedup vs baseline: 1.2617x; 1.2617x over previous
//
#include <hip/hip_runtime.h>
#include <math.h>

#define TT 2048
#define HH 2048
#define ID 768
#define NE 32
#define KTOP 8
#define CAP 1024

typedef short bf16x8 __attribute__((ext_vector_type(8)));
typedef float f32x4 __attribute__((ext_vector_type(4)));

__device__ __forceinline__ unsigned short f2b(float f) {
  unsigned int u = __builtin_bit_cast(unsigned int, f);
  u += 0x7fff + ((u >> 16) & 1);   // round-to-nearest-even
  return (unsigned short)(u >> 16);
}

// ---------------- x -> bf16 pre-convert ----------------
__global__ __launch_bounds__(256) void cvt_x_kernel(const float* __restrict__ x,
                                                    unsigned short* __restrict__ xb) {
  const size_t i = ((size_t)blockIdx.x * 256 + threadIdx.x) * 8;
  const float4 a = *(const float4*)(x + i);
  const float4 b = *(const float4*)(x + i + 4);
  union { unsigned short us[8]; uint4 v; } p;
  p.us[0] = f2b(a.x); p.us[1] = f2b(a.y); p.us[2] = f2b(a.z); p.us[3] = f2b(a.w);
  p.us[4] = f2b(b.x); p.us[5] = f2b(b.y); p.us[6] = f2b(b.z); p.us[7] = f2b(b.w);
  *(uint4*)(xb + i) = p.v;
}

// ---------------- router: logits (f64 acc, parallel) + top-8 + assign ----------------
// One block (256 thr) per token: thread = (expert tid&31, chunk tid>>5 of 256 j).
// 4 independent f64 accumulators/thread -> short dep chains, good ILP.
__global__ __launch_bounds__(256) void router_kernel(
    const float* __restrict__ x, const float* __restrict__ gw,
    const float* __restrict__ gb, int* __restrict__ counts,
    int* __restrict__ tok_slot, float* __restrict__ w_slot) {
  const int t = blockIdx.x;
  const int tid = threadIdx.x;
  const int e = tid & 31;
  const int c = tid >> 5;
  const float* xr = x + (size_t)t * HH;

  __shared__ double pl[8][NE];
  __shared__ float logits[NE];

  double a0 = 0.0, a1 = 0.0, a2 = 0.0, a3 = 0.0;
  const int j0 = c * 256;
#pragma unroll 4
  for (int j = 0; j < 256; j += 4) {
    const int jj = j0 + j;
    a0 = fma((double)xr[jj + 0], (double)gw[(size_t)(jj + 0) * NE + e], a0);
    a1 = fma((double)xr[jj + 1], (double)gw[(size_t)(jj + 1) * NE + e], a1);
    a2 = fma((double)xr[jj + 2], (double)gw[(size_t)(jj + 2) * NE + e], a2);
    a3 = fma((double)xr[jj + 3], (double)gw[(size_t)(jj + 3) * NE + e], a3);
  }
  pl[c][e] = (a0 + a1) + (a2 + a3);
  __syncthreads();

  if (tid < NE) {
    double s = 0.0;
    for (int cc = 0; cc < 8; ++cc) s += pl[cc][tid];
    logits[tid] = (float)s + gb[tid];
  }
  __syncthreads();

  if (tid == 0) {
    float l[NE];
    float m = -1e30f;
    for (int i = 0; i < NE; ++i) { l[i] = logits[i]; m = fmaxf(m, l[i]); }
    int sel[KTOP]; float ex[KTOP]; float s = 0.f;
    for (int k = 0; k < KTOP; ++k) {
      float best = -1e30f; int bi = 0;
      for (int i = 0; i < NE; ++i)
        if (l[i] > best) { best = l[i]; bi = i; }   // strict > : lowest index on ties (jax)
      sel[k] = bi;
      ex[k] = expf(best - m);
      s += ex[k];
      l[bi] = -1e31f;
    }
    const float inv = 1.f / s;
    for (int k = 0; k < KTOP; ++k) {
      const int ee = sel[k];
      const int pos = atomicAdd(&counts[ee], 1);
      if (pos < CAP) {
        tok_slot[ee * CAP + pos] = t;
        w_slot[ee * CAP + pos] = ex[k] * inv;
      }
    }
  }
}

// ---------------- expert gate_up GEMM + SiLU*mul ----------------
// grid: (I/64, CAP/128, E); block 256. Tile: 128(M) x 64(N for g AND u), BK=32.
__global__ __launch_bounds__(256) void gu_kernel(
    const unsigned short* __restrict__ xb, const float* __restrict__ wgu,
    const int* __restrict__ counts, const int* __restrict__ tok_slot,
    unsigned short* __restrict__ h_ws) {
  const int e = blockIdx.z, mt = blockIdx.y, nt = blockIdx.x;
  int cnt = counts[e]; cnt = cnt > CAP ? CAP : cnt;
  if (mt * 128 >= cnt) return;

  __shared__ __align__(16) unsigned short As[128][40];
  __shared__ __align__(16) unsigned short Bg[64][40];
  __shared__ __align__(16) unsigned short Bu[64][40];
  __shared__ int toks[128];

  const int tid = threadIdx.x;
  if (tid < 128) toks[tid] = tok_slot[e * CAP + mt * 128 + tid];
  __syncthreads();

  const float* wg = wgu + (size_t)e * HH * (2 * ID) + nt * 64;
  const float* wu = wg + ID;

  const int wid = tid >> 6, lane = tid & 63;
  const int wm = wid & 1, wn = wid >> 1;
  const int lr = lane & 15, quad = lane >> 4;

  f32x4 accg[4][2], accu[4][2];
  for (int s = 0; s < 4; ++s)
    for (int t = 0; t < 2; ++t)
      for (int r = 0; r < 4; ++r) { accg[s][t][r] = 0.f; accu[s][t][r] = 0.f; }

  for (int k0 = 0; k0 < HH; k0 += 32) {
    // stage A (gathered x rows, already bf16): 128 rows x 32 k
#pragma unroll
    for (int it = 0; it < 2; ++it) {
      const int task = tid + it * 256;
      const int row = task >> 2, cg = task & 3;
      const uint4 v = *(const uint4*)(xb + (size_t)toks[row] * HH + k0 + cg * 8);
      *(uint4*)&As[row][cg * 8] = v;
    }
    // stage B (g and u slices), f32 -> bf16, transposed to [n][k]
#pragma unroll
    for (int it = 0; it < 2; ++it) {
      const int task = tid + it * 256;
      const int k = task >> 4, cg = task & 15;
      const size_t off = (size_t)(k0 + k) * (2 * ID) + cg * 4;
      const float4 vg = *(const float4*)(wg + off);
      const float4 vu = *(const float4*)(wu + off);
      Bg[cg * 4 + 0][k] = f2b(vg.x); Bg[cg * 4 + 1][k] = f2b(vg.y);
      Bg[cg * 4 + 2][k] = f2b(vg.z); Bg[cg * 4 + 3][k] = f2b(vg.w);
      Bu[cg * 4 + 0][k] = f2b(vu.x); Bu[cg * 4 + 1][k] = f2b(vu.y);
      Bu[cg * 4 + 2][k] = f2b(vu.z); Bu[cg * 4 + 3][k] = f2b(vu.w);
    }
    __syncthreads();
    bf16x8 af[4];
#pragma unroll
    for (int s = 0; s < 4; ++s)
      af[s] = *(const bf16x8*)&As[wm * 64 + s * 16 + lr][quad * 8];
#pragma unroll
    for (int t = 0; t < 2; ++t) {
      const bf16x8 bg = *(const bf16x8*)&Bg[wn * 32 + t * 16 + lr][quad * 8];
      const bf16x8 bu = *(const bf16x8*)&Bu[wn * 32 + t * 16 + lr][quad * 8];
#pragma unroll
      for (int s = 0; s < 4; ++s) {
        accg[s][t] = __builtin_amdgcn_mfma_f32_16x16x32_bf16(af[s], bg, accg[s][t], 0, 0, 0);
        accu[s][t] = __builtin_amdgcn_mfma_f32_16x16x32_bf16(af[s], bu, accu[s][t], 0, 0, 0);
      }
    }
    __syncthreads();
  }

  unsigned short* hb = h_ws + (size_t)(e * CAP + mt * 128) * ID + nt * 64;
#pragma unroll
  for (int s = 0; s < 4; ++s)
#pragma unroll
    for (int t = 0; t < 2; ++t)
#pragma unroll
      for (int r = 0; r < 4; ++r) {
        const int row = wm * 64 + s * 16 + quad * 4 + r;
        const int col = wn * 32 + t * 16 + lr;
        const float g = accg[s][t][r], u = accu[s][t][r];
        const float h = (g / (1.f + __expf(-g))) * u;
        hb[(size_t)row * ID + col] = f2b(h);
      }
}

// ---------------- expert down GEMM + weight-scale + scatter-add ----------------
// grid: (H/128, CAP/128, E); block 256. Tile: 128x128, K=768, BK=32.
__global__ __launch_bounds__(256) void down_kernel(
    const unsigned short* __restrict__ h_ws, const float* __restrict__ wd,
    const int* __restrict__ counts, const int* __restrict__ tok_slot,
    const float* __restrict__ w_slot, float* __restrict__ out) {
  const int e = blockIdx.z, mt = blockIdx.y;
  const int nb = blockIdx.x * 128;
  int cnt = counts[e]; cnt = cnt > CAP ? CAP : cnt;
  if (mt * 128 >= cnt) return;

  __shared__ __align__(16) unsigned short As[128][40];
  __shared__ __align__(16) unsigned short Bs[128][40];
  __shared__ int toks[128];
  __shared__ float wr[128];

  const int tid = threadIdx.x;
  if (tid < 128) {
    toks[tid] = tok_slot[e * CAP + mt * 128 + tid];
    wr[tid] = w_slot[e * CAP + mt * 128 + tid];
  }

  const unsigned short* hb = h_ws + (size_t)(e * CAP + mt * 128) * ID;
  const float* wb = wd + (size_t)e * ID * HH + nb;

  const int wid = tid >> 6, lane = tid & 63;
  const int wm = wid & 1, wn = wid >> 1;
  const int lr = lane & 15, quad = lane >> 4;

  f32x4 acc[4][4];
  for (int s = 0; s < 4; ++s)
    for (int t = 0; t < 4; ++t)
      for (int r = 0; r < 4; ++r) acc[s][t][r] = 0.f;

  for (int k0 = 0; k0 < ID; k0 += 32) {
#pragma unroll
    for (int it = 0; it < 2; ++it) {
      const int task = tid + it * 256;
      const int row = task >> 2, cg = task & 3;
      const uint4 v = *(const uint4*)(hb + (size_t)row * ID + k0 + cg * 8);
      *(uint4*)&As[row][cg * 8] = v;
    }
#pragma unroll
    for (int it = 0; it < 4; ++it) {
      const int task = tid + it * 256;
      const int k = task >> 5, cg = task & 31;
      const float4 v = *(const float4*)(wb + (size_t)(k0 + k) * HH + cg * 4);
      Bs[cg * 4 + 0][k] = f2b(v.x); Bs[cg * 4 + 1][k] = f2b(v.y);
      Bs[cg * 4 + 2][k] = f2b(v.z); Bs[cg * 4 + 3][k] = f2b(v.w);
    }
    __syncthreads();
    bf16x8 af[4], bfr[4];
#pragma unroll
    for (int s = 0; s < 4; ++s)
      af[s] = *(const bf16x8*)&As[wm * 64 + s * 16 + lr][quad * 8];
#pragma unroll
    for (int t = 0; t < 4; ++t)
      bfr[t] = *(const bf16x8*)&Bs[wn * 64 + t * 16 + lr][quad * 8];
#pragma unroll
    for (int s = 0; s < 4; ++s)
#pragma unroll
      for (int t = 0; t < 4; ++t)
        acc[s][t] = __builtin_amdgcn_mfma_f32_16x16x32_bf16(af[s], bfr[t], acc[s][t], 0, 0, 0);
    __syncthreads();
  }

#pragma unroll
  for (int s = 0; s < 4; ++s) {
#pragma unroll
    for (int r = 0; r < 4; ++r) {
      const int row = wm * 64 + s * 16 + quad * 4 + r;
      const float w = wr[row];
      if (w != 0.f) {
        const int tk = toks[row];
        float* op = out + (size_t)tk * HH + nb + wn * 64 + lr;
#pragma unroll
        for (int t = 0; t < 4; ++t)
          atomicAdd(op + t * 16, acc[s][t][r] * w);
      }
    }
  }
}

extern "C" void kernel_launch(void* const* d_in, const int* in_sizes, int n_in,
                              void* d_out, int out_size, void* d_ws, size_t ws_size,
                              hipStream_t stream) {
  const float* x   = (const float*)d_in[0];
  const float* gw  = (const float*)d_in[1];
  const float* gb  = (const float*)d_in[2];
  const float* wgu = (const float*)d_in[3];
  const float* wd  = (const float*)d_in[4];
  float* out = (float*)d_out;

  char* ws = (char*)d_ws;
  int*   counts   = (int*)ws;                               // 128 B (pad to 256)
  int*   tok_slot = (int*)(ws + 256);                       // 131072 B
  float* w_slot   = (float*)(ws + 256 + 131072);            // 131072 B
  unsigned short* xb   = (unsigned short*)(ws + 262656);    // 8 MB bf16 x
  unsigned short* h_ws = (unsigned short*)(ws + 262656 + 8388608);  // 50 MB bf16 h

  hipMemsetAsync(d_ws, 0, 262400, stream);                  // counts + slots (w=0 pads)
  hipMemsetAsync(d_out, 0, (size_t)out_size * sizeof(float), stream);

  cvt_x_kernel<<<dim3((TT * HH) / (256 * 8)), dim3(256), 0, stream>>>(x, xb);
  router_kernel<<<dim3(TT), dim3(256), 0, stream>>>(x, gw, gb, counts, tok_slot, w_slot);
  gu_kernel<<<dim3(ID / 64, CAP / 128, NE), dim3(256), 0, stream>>>(xb, wgu, counts, tok_slot, h_ws);
  down_kernel<<<dim3(HH / 128, CAP / 128, NE), dim3(256), 0, stream>>>(h_ws, wd, counts, tok_slot, w_slot, out);
}

// Round 3
// 1146.306 us; speedup vs baseline: 1.4172x; 1.1232x over previous
//
#include <hip/hip_runtime.h>
#include <math.h>

#define TT 2048
#define HH 2048
#define ID 768
#define NE 32
#define KTOP 8
#define CAP 1024

typedef short bf16x8 __attribute__((ext_vector_type(8)));
typedef float f32x4 __attribute__((ext_vector_type(4)));

__device__ __forceinline__ unsigned short f2b(float f) {
  unsigned int u = __builtin_bit_cast(unsigned int, f);
  u += 0x7fff + ((u >> 16) & 1);   // round-to-nearest-even
  return (unsigned short)(u >> 16);
}

__device__ __forceinline__ void gload16(const unsigned short* g, void* l) {
  __builtin_amdgcn_global_load_lds(
      (const __attribute__((address_space(1))) unsigned int*)g,
      (__attribute__((address_space(3))) unsigned int*)l, 16, 0, 0);
}

// ---------------- x -> bf16 pre-convert ----------------
__global__ __launch_bounds__(256) void cvt_x_kernel(const float* __restrict__ x,
                                                    unsigned short* __restrict__ xb) {
  const size_t i = ((size_t)blockIdx.x * 256 + threadIdx.x) * 8;
  const float4 a = *(const float4*)(x + i);
  const float4 b = *(const float4*)(x + i + 4);
  union { unsigned short us[8]; uint4 v; } p;
  p.us[0] = f2b(a.x); p.us[1] = f2b(a.y); p.us[2] = f2b(a.z); p.us[3] = f2b(a.w);
  p.us[4] = f2b(b.x); p.us[5] = f2b(b.y); p.us[6] = f2b(b.z); p.us[7] = f2b(b.w);
  *(uint4*)(xb + i) = p.v;
}

// ---------------- weight transpose+convert: in [E][R][C] f32 -> out [E][C][R] bf16 ----------------
// 64x64 tile via LDS (padded); grid (C/64, R/64, E), block 256.
__global__ __launch_bounds__(256) void cvt_w_kernel(const float* __restrict__ in,
                                                    unsigned short* __restrict__ out,
                                                    int R, int C) {
  __shared__ float tile[64][65];
  const int e = blockIdx.z;
  const int r0 = blockIdx.y * 64, c0 = blockIdx.x * 64;
  const int tid = threadIdx.x;
  const float* src = in + (size_t)e * R * C;
  const int rr = tid >> 4, c4 = tid & 15;
#pragma unroll
  for (int it = 0; it < 4; ++it) {
    const int r = it * 16 + rr;
    const float4 v = *(const float4*)(src + (size_t)(r0 + r) * C + c0 + c4 * 4);
    tile[r][c4 * 4 + 0] = v.x; tile[r][c4 * 4 + 1] = v.y;
    tile[r][c4 * 4 + 2] = v.z; tile[r][c4 * 4 + 3] = v.w;
  }
  __syncthreads();
  unsigned short* dst = out + (size_t)e * R * C;
#pragma unroll
  for (int it = 0; it < 2; ++it) {
    const int task = tid + it * 256;
    const int c = task >> 3, g = task & 7;
    union { unsigned short us[8]; uint4 v; } p;
#pragma unroll
    for (int j = 0; j < 8; ++j) p.us[j] = f2b(tile[g * 8 + j][c]);
    *(uint4*)(dst + (size_t)(c0 + c) * R + r0 + g * 8) = p.v;
  }
}

// ---------------- router: logits (f64 acc, parallel) + top-8 + assign ----------------
__global__ __launch_bounds__(256) void router_kernel(
    const float* __restrict__ x, const float* __restrict__ gw,
    const float* __restrict__ gb, int* __restrict__ counts,
    int* __restrict__ tok_slot, float* __restrict__ w_slot) {
  const int t = blockIdx.x;
  const int tid = threadIdx.x;
  const int e = tid & 31;
  const int c = tid >> 5;
  const float* xr = x + (size_t)t * HH;

  __shared__ double pl[8][NE];
  __shared__ float logits[NE];

  double a0 = 0.0, a1 = 0.0, a2 = 0.0, a3 = 0.0;
  const int j0 = c * 256;
#pragma unroll 4
  for (int j = 0; j < 256; j += 4) {
    const int jj = j0 + j;
    a0 = fma((double)xr[jj + 0], (double)gw[(size_t)(jj + 0) * NE + e], a0);
    a1 = fma((double)xr[jj + 1], (double)gw[(size_t)(jj + 1) * NE + e], a1);
    a2 = fma((double)xr[jj + 2], (double)gw[(size_t)(jj + 2) * NE + e], a2);
    a3 = fma((double)xr[jj + 3], (double)gw[(size_t)(jj + 3) * NE + e], a3);
  }
  pl[c][e] = (a0 + a1) + (a2 + a3);
  __syncthreads();

  if (tid < NE) {
    double s = 0.0;
    for (int cc = 0; cc < 8; ++cc) s += pl[cc][tid];
    logits[tid] = (float)s + gb[tid];
  }
  __syncthreads();

  if (tid == 0) {
    float l[NE];
    float m = -1e30f;
    for (int i = 0; i < NE; ++i) { l[i] = logits[i]; m = fmaxf(m, l[i]); }
    int sel[KTOP]; float ex[KTOP]; float s = 0.f;
    for (int k = 0; k < KTOP; ++k) {
      float best = -1e30f; int bi = 0;
      for (int i = 0; i < NE; ++i)
        if (l[i] > best) { best = l[i]; bi = i; }   // strict > : lowest index on ties (jax)
      sel[k] = bi;
      ex[k] = expf(best - m);
      s += ex[k];
      l[bi] = -1e31f;
    }
    const float inv = 1.f / s;
    for (int k = 0; k < KTOP; ++k) {
      const int ee = sel[k];
      const int pos = atomicAdd(&counts[ee], 1);
      if (pos < CAP) {
        tok_slot[ee * CAP + pos] = t;
        w_slot[ee * CAP + pos] = ex[k] * inv;
      }
    }
  }
}

// ================= NEW PATH: bf16 transposed weights + global_load_lds =================

// gate_up GEMM + SiLU*mul. grid (I/64, CAP/128, E); block 256.
// Tile M=128, N=64(g)+64(u), BK=32. Unpadded LDS (global_load_lds requirement).
__global__ __launch_bounds__(256) void gu2_kernel(
    const unsigned short* __restrict__ xb, const unsigned short* __restrict__ wguT,
    const int* __restrict__ counts, const int* __restrict__ tok_slot,
    unsigned short* __restrict__ h_ws) {
  const int e = blockIdx.z, mt = blockIdx.y, nt = blockIdx.x;
  int cnt = counts[e]; cnt = cnt > CAP ? CAP : cnt;
  if (mt * 128 >= cnt) return;

  __shared__ __align__(16) unsigned short As[128 * 32];
  __shared__ __align__(16) unsigned short Bg[64 * 32];
  __shared__ __align__(16) unsigned short Bu[64 * 32];
  __shared__ int toks[128];

  const int tid = threadIdx.x;
  if (tid < 128) toks[tid] = tok_slot[e * CAP + mt * 128 + tid];
  __syncthreads();

  const unsigned short* bgp = wguT + (size_t)e * (2 * ID) * HH + (size_t)(nt * 64) * HH;
  const unsigned short* bup = bgp + (size_t)ID * HH;

  const int wv = tid >> 6;
  const int ar = tid >> 2, cg = tid & 3;
  char* ldsA0 = (char*)As + wv * 1024;
  char* ldsA1 = (char*)As + 4096 + wv * 1024;
  char* ldsBg = (char*)Bg + wv * 1024;
  char* ldsBu = (char*)Bu + wv * 1024;
  const unsigned short* srcA0 = xb + (size_t)toks[ar] * HH + cg * 8;
  const unsigned short* srcA1 = xb + (size_t)toks[ar + 64] * HH + cg * 8;
  const unsigned short* srcBg = bgp + (size_t)ar * HH + cg * 8;
  const unsigned short* srcBu = bup + (size_t)ar * HH + cg * 8;

  const int wid = tid >> 6, lane = tid & 63;
  const int wm = wid & 1, wn = wid >> 1;
  const int lr = lane & 15, quad = lane >> 4;

  f32x4 accg[4][2], accu[4][2];
  for (int s = 0; s < 4; ++s)
    for (int t = 0; t < 2; ++t)
      for (int r = 0; r < 4; ++r) { accg[s][t][r] = 0.f; accu[s][t][r] = 0.f; }

  for (int k0 = 0; k0 < HH; k0 += 32) {
    gload16(srcA0 + k0, ldsA0);
    gload16(srcA1 + k0, ldsA1);
    gload16(srcBg + k0, ldsBg);
    gload16(srcBu + k0, ldsBu);
    __syncthreads();
    bf16x8 af[4];
#pragma unroll
    for (int s = 0; s < 4; ++s)
      af[s] = *(const bf16x8*)&As[(wm * 64 + s * 16 + lr) * 32 + quad * 8];
#pragma unroll
    for (int t = 0; t < 2; ++t) {
      const bf16x8 bg = *(const bf16x8*)&Bg[(wn * 32 + t * 16 + lr) * 32 + quad * 8];
      const bf16x8 bu = *(const bf16x8*)&Bu[(wn * 32 + t * 16 + lr) * 32 + quad * 8];
#pragma unroll
      for (int s = 0; s < 4; ++s) {
        accg[s][t] = __builtin_amdgcn_mfma_f32_16x16x32_bf16(af[s], bg, accg[s][t], 0, 0, 0);
        accu[s][t] = __builtin_amdgcn_mfma_f32_16x16x32_bf16(af[s], bu, accu[s][t], 0, 0, 0);
      }
    }
    __syncthreads();
  }

  unsigned short* hb = h_ws + (size_t)(e * CAP + mt * 128) * ID + nt * 64;
#pragma unroll
  for (int s = 0; s < 4; ++s)
#pragma unroll
    for (int t = 0; t < 2; ++t)
#pragma unroll
      for (int r = 0; r < 4; ++r) {
        const int row = wm * 64 + s * 16 + quad * 4 + r;
        const int col = wn * 32 + t * 16 + lr;
        const float g = accg[s][t][r], u = accu[s][t][r];
        const float h = (g / (1.f + __expf(-g))) * u;
        hb[(size_t)row * ID + col] = f2b(h);
      }
}

// down GEMM + weight-scale + scatter-add. grid (H/128, CAP/128, E); block 256.
__global__ __launch_bounds__(256) void down2_kernel(
    const unsigned short* __restrict__ h_ws, const unsigned short* __restrict__ wdT,
    const int* __restrict__ counts, const int* __restrict__ tok_slot,
    const float* __restrict__ w_slot, float* __restrict__ out) {
  const int e = blockIdx.z, mt = blockIdx.y;
  const int nb = blockIdx.x * 128;
  int cnt = counts[e]; cnt = cnt > CAP ? CAP : cnt;
  if (mt * 128 >= cnt) return;

  __shared__ __align__(16) unsigned short As[128 * 32];
  __shared__ __align__(16) unsigned short Bs[128 * 32];
  __shared__ int toks[128];
  __shared__ float wr[128];

  const int tid = threadIdx.x;
  if (tid < 128) {
    toks[tid] = tok_slot[e * CAP + mt * 128 + tid];
    wr[tid] = w_slot[e * CAP + mt * 128 + tid];
  }
  __syncthreads();

  const unsigned short* hb = h_ws + (size_t)(e * CAP + mt * 128) * ID;
  const unsigned short* wb = wdT + (size_t)e * HH * ID + (size_t)nb * ID;

  const int wv = tid >> 6;
  const int ar = tid >> 2, cg = tid & 3;
  char* ldsA0 = (char*)As + wv * 1024;
  char* ldsA1 = (char*)As + 4096 + wv * 1024;
  char* ldsB0 = (char*)Bs + wv * 1024;
  char* ldsB1 = (char*)Bs + 4096 + wv * 1024;
  const unsigned short* srcA0 = hb + (size_t)ar * ID + cg * 8;
  const unsigned short* srcA1 = hb + (size_t)(ar + 64) * ID + cg * 8;
  const unsigned short* srcB0 = wb + (size_t)ar * ID + cg * 8;
  const unsigned short* srcB1 = wb + (size_t)(ar + 64) * ID + cg * 8;

  const int wid = tid >> 6, lane = tid & 63;
  const int wm = wid & 1, wn = wid >> 1;
  const int lr = lane & 15, quad = lane >> 4;

  f32x4 acc[4][4];
  for (int s = 0; s < 4; ++s)
    for (int t = 0; t < 4; ++t)
      for (int r = 0; r < 4; ++r) acc[s][t][r] = 0.f;

  for (int k0 = 0; k0 < ID; k0 += 32) {
    gload16(srcA0 + k0, ldsA0);
    gload16(srcA1 + k0, ldsA1);
    gload16(srcB0 + k0, ldsB0);
    gload16(srcB1 + k0, ldsB1);
    __syncthreads();
    bf16x8 af[4], bfr[4];
#pragma unroll
    for (int s = 0; s < 4; ++s)
      af[s] = *(const bf16x8*)&As[(wm * 64 + s * 16 + lr) * 32 + quad * 8];
#pragma unroll
    for (int t = 0; t < 4; ++t)
      bfr[t] = *(const bf16x8*)&Bs[(wn * 64 + t * 16 + lr) * 32 + quad * 8];
#pragma unroll
    for (int s = 0; s < 4; ++s)
#pragma unroll
      for (int t = 0; t < 4; ++t)
        acc[s][t] = __builtin_amdgcn_mfma_f32_16x16x32_bf16(af[s], bfr[t], acc[s][t], 0, 0, 0);
    __syncthreads();
  }

#pragma unroll
  for (int s = 0; s < 4; ++s) {
#pragma unroll
    for (int r = 0; r < 4; ++r) {
      const int row = wm * 64 + s * 16 + quad * 4 + r;
      const float w = wr[row];
      if (w != 0.f) {
        const int tk = toks[row];
        float* op = out + (size_t)tk * HH + nb + wn * 64 + lr;
#pragma unroll
        for (int t = 0; t < 4; ++t)
          atomicAdd(op + t * 16, acc[s][t][r] * w);
      }
    }
  }
}

// ================= LEGACY PATH (fallback if ws too small): convert-in-GEMM =================

__global__ __launch_bounds__(256) void gu_kernel(
    const unsigned short* __restrict__ xb, const float* __restrict__ wgu,
    const int* __restrict__ counts, const int* __restrict__ tok_slot,
    unsigned short* __restrict__ h_ws) {
  const int e = blockIdx.z, mt = blockIdx.y, nt = blockIdx.x;
  int cnt = counts[e]; cnt = cnt > CAP ? CAP : cnt;
  if (mt * 128 >= cnt) return;

  __shared__ __align__(16) unsigned short As[128][40];
  __shared__ __align__(16) unsigned short Bg[64][40];
  __shared__ __align__(16) unsigned short Bu[64][40];
  __shared__ int toks[128];

  const int tid = threadIdx.x;
  if (tid < 128) toks[tid] = tok_slot[e * CAP + mt * 128 + tid];
  __syncthreads();

  const float* wg = wgu + (size_t)e * HH * (2 * ID) + nt * 64;
  const float* wu = wg + ID;

  const int wid = tid >> 6, lane = tid & 63;
  const int wm = wid & 1, wn = wid >> 1;
  const int lr = lane & 15, quad = lane >> 4;

  f32x4 accg[4][2], accu[4][2];
  for (int s = 0; s < 4; ++s)
    for (int t = 0; t < 2; ++t)
      for (int r = 0; r < 4; ++r) { accg[s][t][r] = 0.f; accu[s][t][r] = 0.f; }

  for (int k0 = 0; k0 < HH; k0 += 32) {
#pragma unroll
    for (int it = 0; it < 2; ++it) {
      const int task = tid + it * 256;
      const int row = task >> 2, cg = task & 3;
      const uint4 v = *(const uint4*)(xb + (size_t)toks[row] * HH + k0 + cg * 8);
      *(uint4*)&As[row][cg * 8] = v;
    }
#pragma unroll
    for (int it = 0; it < 2; ++it) {
      const int task = tid + it * 256;
      const int k = task >> 4, cg = task & 15;
      const size_t off = (size_t)(k0 + k) * (2 * ID) + cg * 4;
      const float4 vg = *(const float4*)(wg + off);
      const float4 vu = *(const float4*)(wu + off);
      Bg[cg * 4 + 0][k] = f2b(vg.x); Bg[cg * 4 + 1][k] = f2b(vg.y);
      Bg[cg * 4 + 2][k] = f2b(vg.z); Bg[cg * 4 + 3][k] = f2b(vg.w);
      Bu[cg * 4 + 0][k] = f2b(vu.x); Bu[cg * 4 + 1][k] = f2b(vu.y);
      Bu[cg * 4 + 2][k] = f2b(vu.z); Bu[cg * 4 + 3][k] = f2b(vu.w);
    }
    __syncthreads();
    bf16x8 af[4];
#pragma unroll
    for (int s = 0; s < 4; ++s)
      af[s] = *(const bf16x8*)&As[wm * 64 + s * 16 + lr][quad * 8];
#pragma unroll
    for (int t = 0; t < 2; ++t) {
      const bf16x8 bg = *(const bf16x8*)&Bg[wn * 32 + t * 16 + lr][quad * 8];
      const bf16x8 bu = *(const bf16x8*)&Bu[wn * 32 + t * 16 + lr][quad * 8];
#pragma unroll
      for (int s = 0; s < 4; ++s) {
        accg[s][t] = __builtin_amdgcn_mfma_f32_16x16x32_bf16(af[s], bg, accg[s][t], 0, 0, 0);
        accu[s][t] = __builtin_amdgcn_mfma_f32_16x16x32_bf16(af[s], bu, accu[s][t], 0, 0, 0);
      }
    }
    __syncthreads();
  }

  unsigned short* hb = h_ws + (size_t)(e * CAP + mt * 128) * ID + nt * 64;
#pragma unroll
  for (int s = 0; s < 4; ++s)
#pragma unroll
    for (int t = 0; t < 2; ++t)
#pragma unroll
      for (int r = 0; r < 4; ++r) {
        const int row = wm * 64 + s * 16 + quad * 4 + r;
        const int col = wn * 32 + t * 16 + lr;
        const float g = accg[s][t][r], u = accu[s][t][r];
        const float h = (g / (1.f + __expf(-g))) * u;
        hb[(size_t)row * ID + col] = f2b(h);
      }
}

__global__ __launch_bounds__(256) void down_kernel(
    const unsigned short* __restrict__ h_ws, const float* __restrict__ wd,
    const int* __restrict__ counts, const int* __restrict__ tok_slot,
    const float* __restrict__ w_slot, float* __restrict__ out) {
  const int e = blockIdx.z, mt = blockIdx.y;
  const int nb = blockIdx.x * 128;
  int cnt = counts[e]; cnt = cnt > CAP ? CAP : cnt;
  if (mt * 128 >= cnt) return;

  __shared__ __align__(16) unsigned short As[128][40];
  __shared__ __align__(16) unsigned short Bs[128][40];
  __shared__ int toks[128];
  __shared__ float wr[128];

  const int tid = threadIdx.x;
  if (tid < 128) {
    toks[tid] = tok_slot[e * CAP + mt * 128 + tid];
    wr[tid] = w_slot[e * CAP + mt * 128 + tid];
  }

  const unsigned short* hb = h_ws + (size_t)(e * CAP + mt * 128) * ID;
  const float* wb = wd + (size_t)e * ID * HH + nb;

  const int wid = tid >> 6, lane = tid & 63;
  const int wm = wid & 1, wn = wid >> 1;
  const int lr = lane & 15, quad = lane >> 4;

  f32x4 acc[4][4];
  for (int s = 0; s < 4; ++s)
    for (int t = 0; t < 4; ++t)
      for (int r = 0; r < 4; ++r) acc[s][t][r] = 0.f;

  for (int k0 = 0; k0 < ID; k0 += 32) {
#pragma unroll
    for (int it = 0; it < 2; ++it) {
      const int task = tid + it * 256;
      const int row = task >> 2, cg = task & 3;
      const uint4 v = *(const uint4*)(hb + (size_t)row * ID + k0 + cg * 8);
      *(uint4*)&As[row][cg * 8] = v;
    }
#pragma unroll
    for (int it = 0; it < 4; ++it) {
      const int task = tid + it * 256;
      const int k = task >> 5, cg = task & 31;
      const float4 v = *(const float4*)(wb + (size_t)(k0 + k) * HH + cg * 4);
      Bs[cg * 4 + 0][k] = f2b(v.x); Bs[cg * 4 + 1][k] = f2b(v.y);
      Bs[cg * 4 + 2][k] = f2b(v.z); Bs[cg * 4 + 3][k] = f2b(v.w);
    }
    __syncthreads();
    bf16x8 af[4], bfr[4];
#pragma unroll
    for (int s = 0; s < 4; ++s)
      af[s] = *(const bf16x8*)&As[wm * 64 + s * 16 + lr][quad * 8];
#pragma unroll
    for (int t = 0; t < 4; ++t)
      bfr[t] = *(const bf16x8*)&Bs[wn * 64 + t * 16 + lr][quad * 8];
#pragma unroll
    for (int s = 0; s < 4; ++s)
#pragma unroll
      for (int t = 0; t < 4; ++t)
        acc[s][t] = __builtin_amdgcn_mfma_f32_16x16x32_bf16(af[s], bfr[t], acc[s][t], 0, 0, 0);
    __syncthreads();
  }

#pragma unroll
  for (int s = 0; s < 4; ++s) {
#pragma unroll
    for (int r = 0; r < 4; ++r) {
      const int row = wm * 64 + s * 16 + quad * 4 + r;
      const float w = wr[row];
      if (w != 0.f) {
        const int tk = toks[row];
        float* op = out + (size_t)tk * HH + nb + wn * 64 + lr;
#pragma unroll
        for (int t = 0; t < 4; ++t)
          atomicAdd(op + t * 16, acc[s][t][r] * w);
      }
    }
  }
}

extern "C" void kernel_launch(void* const* d_in, const int* in_sizes, int n_in,
                              void* d_out, int out_size, void* d_ws, size_t ws_size,
                              hipStream_t stream) {
  const float* x   = (const float*)d_in[0];
  const float* gw  = (const float*)d_in[1];
  const float* gb  = (const float*)d_in[2];
  const float* wgu = (const float*)d_in[3];
  const float* wd  = (const float*)d_in[4];
  float* out = (float*)d_out;

  char* ws = (char*)d_ws;
  int*   counts   = (int*)ws;                                       // 256 B
  int*   tok_slot = (int*)(ws + 256);                               // 131072 B
  float* w_slot   = (float*)(ws + 256 + 131072);                    // 131072 B
  unsigned short* xb   = (unsigned short*)(ws + 262656);            // 8 MB
  unsigned short* h_ws = (unsigned short*)(ws + 8651264);           // 50.3 MB
  unsigned short* wguT = (unsigned short*)(ws + 58982912);          // 201.3 MB
  unsigned short* wdT  = (unsigned short*)(ws + 260309504);         // 100.7 MB
  const size_t NEED = 360972800ULL;

  hipMemsetAsync(d_ws, 0, 262400, stream);                          // counts + slots
  hipMemsetAsync(d_out, 0, (size_t)out_size * sizeof(float), stream);

  cvt_x_kernel<<<dim3((TT * HH) / (256 * 8)), dim3(256), 0, stream>>>(x, xb);
  router_kernel<<<dim3(TT), dim3(256), 0, stream>>>(x, gw, gb, counts, tok_slot, w_slot);

  if (ws_size >= NEED) {
    cvt_w_kernel<<<dim3((2 * ID) / 64, HH / 64, NE), dim3(256), 0, stream>>>(wgu, wguT, HH, 2 * ID);
    cvt_w_kernel<<<dim3(HH / 64, ID / 64, NE), dim3(256), 0, stream>>>(wd, wdT, ID, HH);
    gu2_kernel<<<dim3(ID / 64, CAP / 128, NE), dim3(256), 0, stream>>>(xb, wguT, counts, tok_slot, h_ws);
    down2_kernel<<<dim3(HH / 128, CAP / 128, NE), dim3(256), 0, stream>>>(h_ws, wdT, counts, tok_slot, w_slot, out);
  } else {
    gu_kernel<<<dim3(ID / 64, CAP / 128, NE), dim3(256), 0, stream>>>(xb, wgu, counts, tok_slot, h_ws);
    down_kernel<<<dim3(HH / 128, CAP / 128, NE), dim3(256), 0, stream>>>(h_ws, wd, counts, tok_slot, w_slot, out);
  }
}